// Round 1
// baseline (2168.390 us; speedup 1.0000x reference)
//
#include <hip/hip_runtime.h>

#define THREADS 256

// ---- degree accumulation: deg_out[src[e]] += 1, deg_in[dst[e]] += 1 ----
__global__ void degree_kernel(const int* __restrict__ src, const int* __restrict__ dst,
                              float* __restrict__ deg_out, float* __restrict__ deg_in, int E) {
    int e = blockIdx.x * blockDim.x + threadIdx.x;
    if (e < E) {
        atomicAdd(&deg_out[src[e]], 1.0f);
        atomicAdd(&deg_in[dst[e]], 1.0f);
    }
}

// ---- rnorm: d = clip(d,1)^-0.5, in place for both arrays ----
__global__ void rnorm_kernel(float* __restrict__ deg_out, float* __restrict__ deg_in, int n) {
    int i = blockIdx.x * blockDim.x + threadIdx.x;
    if (i < n) {
        deg_out[i] = rsqrtf(fmaxf(deg_out[i], 1.0f));
        deg_in[i]  = rsqrtf(fmaxf(deg_in[i], 1.0f));
    }
}

// ---- h[node, :] = (x[node, :] * norm[node]) @ W ;  W is [128][OUT] row-major ----
// One wave per node. W staged in LDS in 64-col halves (32KB). 4 waves/block.
template<int OUT>
__global__ __launch_bounds__(256) void gemm_kernel(const float* __restrict__ x,
                                                   const float* __restrict__ W,
                                                   const float* __restrict__ norm,
                                                   float* __restrict__ h, int n) {
    __shared__ float Wl[128 * 64];   // 32 KB: one 64-col half of W
    __shared__ float xr[4][128];     // per-wave x row (scaled)
    const int wave = threadIdx.x >> 6;
    const int lane = threadIdx.x & 63;

    #pragma unroll
    for (int half = 0; half < OUT / 64; ++half) {
        __syncthreads();
        // cooperative load of W[:, half*64 .. half*64+64)
        for (int t = threadIdx.x; t < 128 * 64; t += THREADS) {
            int k = t >> 6, j = t & 63;
            Wl[t] = W[k * OUT + half * 64 + j];
        }
        __syncthreads();

        for (int node = blockIdx.x * 4 + wave; node < n; node += gridDim.x * 4) {
            float nf = norm[node];
            xr[wave][lane]      = x[(size_t)node * 128 + lane] * nf;
            xr[wave][lane + 64] = x[(size_t)node * 128 + lane + 64] * nf;
            // wave-private LDS; compiler inserts lgkmcnt waits for the RAW dep
            float acc = 0.0f;
            #pragma unroll
            for (int k = 0; k < 128; ++k)
                acc += xr[wave][k] * Wl[k * 64 + lane];
            h[(size_t)node * OUT + half * 64 + lane] = acc;
        }
    }
}

// ---- scatter-add: agg[dst[e], :] += h[src[e], :]  (one wave per edge) ----
template<int OUT>
__global__ __launch_bounds__(256) void scatter_kernel(const float* __restrict__ h,
                                                      const int* __restrict__ src,
                                                      const int* __restrict__ dst,
                                                      float* __restrict__ agg, int E) {
    int e = (int)((blockIdx.x * (size_t)blockDim.x + threadIdx.x) >> 6);
    int lane = threadIdx.x & 63;
    if (e >= E) return;
    int s = src[e], d = dst[e];
    atomicAdd(&agg[(size_t)d * OUT + lane], h[(size_t)s * OUT + lane]);
    if (OUT > 64)
        atomicAdd(&agg[(size_t)d * OUT + lane + 64], h[(size_t)s * OUT + lane + 64]);
}

// ---- finalize: out = (agg * norm_in[:,None] + b) [relu] ----
template<int OUT, bool RELU>
__global__ void finalize_kernel(const float* __restrict__ agg, const float* __restrict__ nin,
                                const float* __restrict__ b, float* __restrict__ out, int n) {
    int i4 = blockIdx.x * blockDim.x + threadIdx.x;
    int total = n * OUT / 4;
    if (i4 >= total) return;
    int elem = i4 * 4;
    int node = elem >> (OUT == 128 ? 7 : 6);
    int col  = elem & (OUT - 1);
    float s = nin[node];
    float4 a  = *(const float4*)(agg + elem);
    float4 bb = *(const float4*)(b + col);
    float4 r;
    r.x = a.x * s + bb.x;
    r.y = a.y * s + bb.y;
    r.z = a.z * s + bb.z;
    r.w = a.w * s + bb.w;
    if (RELU) {
        r.x = fmaxf(r.x, 0.0f);
        r.y = fmaxf(r.y, 0.0f);
        r.z = fmaxf(r.z, 0.0f);
        r.w = fmaxf(r.w, 0.0f);
    }
    *(float4*)(out + elem) = r;
}

extern "C" void kernel_launch(void* const* d_in, const int* in_sizes, int n_in,
                              void* d_out, int out_size, void* d_ws, size_t ws_size,
                              hipStream_t stream) {
    const float* in_feat = (const float*)d_in[0];
    const int*   src     = (const int*)d_in[1];
    const int*   dst     = (const int*)d_in[2];
    const float* W1      = (const float*)d_in[3];
    const float* b1      = (const float*)d_in[4];
    const float* W2      = (const float*)d_in[5];
    const float* b2      = (const float*)d_in[6];
    const float* W3      = (const float*)d_in[7];
    const float* b3      = (const float*)d_in[8];

    const int n = in_sizes[0] / 128;
    const int E = in_sizes[1];
    float* out = (float*)d_out;

    float* ws      = (float*)d_ws;
    float* deg_out = ws;                       // n  (becomes norm_out)
    float* deg_in  = ws + n;                   // n  (becomes norm_in)
    float* bufA    = ws + 2 * (size_t)n;       // n*128
    float* bufB    = bufA + (size_t)n * 128;   // n*128

    // degrees -> rnorm
    hipMemsetAsync(deg_out, 0, 2 * (size_t)n * sizeof(float), stream);
    degree_kernel<<<(E + THREADS - 1) / THREADS, THREADS, 0, stream>>>(src, dst, deg_out, deg_in, E);
    rnorm_kernel<<<(n + THREADS - 1) / THREADS, THREADS, 0, stream>>>(deg_out, deg_in, n);

    const int gemm_grid = 1024;
    const int scat_grid = (E + 3) / 4;   // one wave (of 4/block) per edge

    // ---- layer 1 ----
    gemm_kernel<128><<<gemm_grid, THREADS, 0, stream>>>(in_feat, W1, deg_out, bufA, n);
    hipMemsetAsync(bufB, 0, (size_t)n * 128 * sizeof(float), stream);
    scatter_kernel<128><<<scat_grid, THREADS, 0, stream>>>(bufA, src, dst, bufB, E);
    finalize_kernel<128, true><<<((size_t)n * 128 / 4 + THREADS - 1) / THREADS, THREADS, 0, stream>>>(
        bufB, deg_in, b1, bufB, n);

    // ---- layer 2 ----
    gemm_kernel<128><<<gemm_grid, THREADS, 0, stream>>>(bufB, W2, deg_out, bufA, n);
    hipMemsetAsync(bufB, 0, (size_t)n * 128 * sizeof(float), stream);
    scatter_kernel<128><<<scat_grid, THREADS, 0, stream>>>(bufA, src, dst, bufB, E);
    finalize_kernel<128, true><<<((size_t)n * 128 / 4 + THREADS - 1) / THREADS, THREADS, 0, stream>>>(
        bufB, deg_in, b2, bufB, n);

    // ---- layer 3 ----
    gemm_kernel<64><<<gemm_grid, THREADS, 0, stream>>>(bufB, W3, deg_out, bufA, n);
    hipMemsetAsync(bufB, 0, (size_t)n * 64 * sizeof(float), stream);
    scatter_kernel<64><<<scat_grid, THREADS, 0, stream>>>(bufA, src, dst, bufB, E);
    finalize_kernel<64, false><<<((size_t)n * 64 / 4 + THREADS - 1) / THREADS, THREADS, 0, stream>>>(
        bufB, deg_in, b3, out, n);
}

// Round 2
// 915.242 us; speedup vs baseline: 2.3692x; 2.3692x over previous
//
#include <hip/hip_runtime.h>

#define THREADS 256
#define SCAN_BLK 1024   // counts per scan block (256 threads x 4)

// ---- degree counts (int atomics) ----
__global__ void degree_kernel(const int* __restrict__ src, const int* __restrict__ dst,
                              int* __restrict__ cnt_out, int* __restrict__ cnt_in, int E) {
    int e = blockIdx.x * blockDim.x + threadIdx.x;
    if (e < E) {
        atomicAdd(&cnt_out[src[e]], 1);
        atomicAdd(&cnt_in[dst[e]], 1);
    }
}

// ---- norm = clip(deg,1)^-0.5 ----
__global__ void rnorm_kernel(const int* __restrict__ cnt_out, const int* __restrict__ cnt_in,
                             float* __restrict__ norm_out, float* __restrict__ norm_in, int n) {
    int i = blockIdx.x * blockDim.x + threadIdx.x;
    if (i < n) {
        norm_out[i] = rsqrtf((float)max(cnt_out[i], 1));
        norm_in[i]  = rsqrtf((float)max(cnt_in[i], 1));
    }
}

// ---- exclusive scan of cnt_in -> row_off (3-phase) ----
__global__ void scan_phase1(const int* __restrict__ cnt, int* __restrict__ blk_sums, int n) {
    int base = blockIdx.x * SCAN_BLK;
    int t = threadIdx.x;
    int sum = 0;
    for (int i = t; i < SCAN_BLK; i += THREADS) {
        int idx = base + i;
        sum += (idx < n) ? cnt[idx] : 0;
    }
    __shared__ int wsum[4];
    for (int off = 32; off > 0; off >>= 1) sum += __shfl_down(sum, off);
    if ((t & 63) == 0) wsum[t >> 6] = sum;
    __syncthreads();
    if (t == 0) blk_sums[blockIdx.x] = wsum[0] + wsum[1] + wsum[2] + wsum[3];
}

__global__ void scan_phase2(int* __restrict__ blk_sums, int nb) {
    __shared__ int s[1024];
    int t = threadIdx.x;
    s[t] = (t < nb) ? blk_sums[t] : 0;
    __syncthreads();
    for (int off = 1; off < 1024; off <<= 1) {
        int v = s[t];
        if (t >= off) v += s[t - off];
        __syncthreads();
        s[t] = v;
        __syncthreads();
    }
    if (t < nb) blk_sums[t] = (t == 0) ? 0 : s[t - 1];
}

__global__ void scan_phase3(const int* __restrict__ cnt, const int* __restrict__ blk_sums,
                            int* __restrict__ row_off, int n, int E) {
    __shared__ int ts[THREADS];
    int b = blockIdx.x, t = threadIdx.x;
    int base = b * SCAN_BLK + t * 4;
    int local[4]; int s = 0;
    #pragma unroll
    for (int k = 0; k < 4; ++k) {
        local[k] = s;
        int idx = base + k;
        s += (idx < n) ? cnt[idx] : 0;
    }
    ts[t] = s;
    __syncthreads();
    for (int off = 1; off < THREADS; off <<= 1) {
        int v = ts[t];
        if (t >= off) v += ts[t - off];
        __syncthreads();
        ts[t] = v;
        __syncthreads();
    }
    int excl = (t == 0) ? 0 : ts[t - 1];
    int boff = blk_sums[b];
    #pragma unroll
    for (int k = 0; k < 4; ++k) {
        int idx = base + k;
        if (idx < n) row_off[idx] = boff + excl + local[k];
    }
    if (b == 0 && t == 0) row_off[n] = E;
}

// ---- bucket edges by dst: csr_src[row_off[d] + cursor[d]++] = src ----
__global__ void fill_kernel(const int* __restrict__ src, const int* __restrict__ dst,
                            const int* __restrict__ row_off, int* __restrict__ cursor,
                            int* __restrict__ csr_src, int E) {
    int e = blockIdx.x * blockDim.x + threadIdx.x;
    if (e < E) {
        int d = dst[e];
        int pos = row_off[d] + atomicAdd(&cursor[d], 1);
        csr_src[pos] = src[e];
    }
}

// ---- h[node, :] = (x[node, :] * norm[node]) @ W ;  W is [128][OUT] row-major ----
template<int OUT>
__global__ __launch_bounds__(256) void gemm_kernel(const float* __restrict__ x,
                                                   const float* __restrict__ W,
                                                   const float* __restrict__ norm,
                                                   float* __restrict__ h, int n) {
    __shared__ float Wl[128 * 64];   // 32 KB: one 64-col half of W
    __shared__ float xr[4][128];     // per-wave x row (scaled)
    const int wave = threadIdx.x >> 6;
    const int lane = threadIdx.x & 63;

    #pragma unroll
    for (int half = 0; half < OUT / 64; ++half) {
        __syncthreads();
        for (int t = threadIdx.x; t < 128 * 64; t += THREADS) {
            int k = t >> 6, j = t & 63;
            Wl[t] = W[k * OUT + half * 64 + j];
        }
        __syncthreads();

        for (int node = blockIdx.x * 4 + wave; node < n; node += gridDim.x * 4) {
            float nf = norm[node];
            xr[wave][lane]      = x[(size_t)node * 128 + lane] * nf;
            xr[wave][lane + 64] = x[(size_t)node * 128 + lane + 64] * nf;
            float acc = 0.0f;
            #pragma unroll
            for (int k = 0; k < 128; ++k)
                acc += xr[wave][k] * Wl[k * 64 + lane];
            h[(size_t)node * OUT + half * 64 + lane] = acc;
        }
    }
}

// ---- CSR aggregation + fused finalize: out[d,:] = relu(norm_in[d]*sum_{s in N(d)} h[s,:] + b) ----
template<int OUT, bool RELU>
__global__ __launch_bounds__(256) void agg_kernel(const float* __restrict__ h,
                                                  const int* __restrict__ row_off,
                                                  const int* __restrict__ csr_src,
                                                  const float* __restrict__ nin,
                                                  const float* __restrict__ bias,
                                                  float* __restrict__ out, int n) {
    const int wave = threadIdx.x >> 6;
    const int lane = threadIdx.x & 63;
    for (int node = blockIdx.x * 4 + wave; node < n; node += gridDim.x * 4) {
        int beg = row_off[node], end = row_off[node + 1];
        float a0 = 0.0f, a1 = 0.0f;
        int j = beg;
        for (; j + 1 < end; j += 2) {
            int s0 = csr_src[j], s1 = csr_src[j + 1];
            a0 += h[(size_t)s0 * OUT + lane];
            if (OUT > 64) a1 += h[(size_t)s0 * OUT + 64 + lane];
            a0 += h[(size_t)s1 * OUT + lane];
            if (OUT > 64) a1 += h[(size_t)s1 * OUT + 64 + lane];
        }
        if (j < end) {
            int s0 = csr_src[j];
            a0 += h[(size_t)s0 * OUT + lane];
            if (OUT > 64) a1 += h[(size_t)s0 * OUT + 64 + lane];
        }
        float nf = nin[node];
        float r0 = a0 * nf + bias[lane];
        if (RELU) r0 = fmaxf(r0, 0.0f);
        out[(size_t)node * OUT + lane] = r0;
        if (OUT > 64) {
            float r1 = a1 * nf + bias[64 + lane];
            if (RELU) r1 = fmaxf(r1, 0.0f);
            out[(size_t)node * OUT + 64 + lane] = r1;
        }
    }
}

extern "C" void kernel_launch(void* const* d_in, const int* in_sizes, int n_in,
                              void* d_out, int out_size, void* d_ws, size_t ws_size,
                              hipStream_t stream) {
    const float* in_feat = (const float*)d_in[0];
    const int*   src     = (const int*)d_in[1];
    const int*   dst     = (const int*)d_in[2];
    const float* W1      = (const float*)d_in[3];
    const float* b1      = (const float*)d_in[4];
    const float* W2      = (const float*)d_in[5];
    const float* b2      = (const float*)d_in[6];
    const float* W3      = (const float*)d_in[7];
    const float* b3      = (const float*)d_in[8];

    const int n = in_sizes[0] / 128;
    const int E = in_sizes[1];
    float* out = (float*)d_out;

    // workspace layout (persistent): norm_out, norm_in, row_off[n+2], csr_src[E], bufA, bufB
    float* ws       = (float*)d_ws;
    float* norm_out = ws;
    float* norm_in  = ws + n;
    int*   row_off  = (int*)(ws + 2 * (size_t)n);
    int*   csr_src  = row_off + (n + 2);
    float* bufA     = (float*)(csr_src + E);
    float* bufB     = bufA + (size_t)n * 128;
    // CSR-build temporaries overlaid on bufA (dead before gemm layer 1 writes bufA)
    int* cnt_out  = (int*)bufA;
    int* cnt_in   = cnt_out + n;
    int* cursor   = cnt_in + n;
    int* blk_sums = cursor + n;

    const int nb = (n + SCAN_BLK - 1) / SCAN_BLK;

    // ---- CSR build + norms (once, reused by all 3 layers) ----
    hipMemsetAsync(cnt_out, 0, 3 * (size_t)n * sizeof(int), stream);
    degree_kernel<<<(E + THREADS - 1) / THREADS, THREADS, 0, stream>>>(src, dst, cnt_out, cnt_in, E);
    rnorm_kernel<<<(n + THREADS - 1) / THREADS, THREADS, 0, stream>>>(cnt_out, cnt_in, norm_out, norm_in, n);
    scan_phase1<<<nb, THREADS, 0, stream>>>(cnt_in, blk_sums, n);
    scan_phase2<<<1, 1024, 0, stream>>>(blk_sums, nb);
    scan_phase3<<<nb, THREADS, 0, stream>>>(cnt_in, blk_sums, row_off, n, E);
    fill_kernel<<<(E + THREADS - 1) / THREADS, THREADS, 0, stream>>>(src, dst, row_off, cursor, csr_src, E);

    const int gemm_grid = 1024;
    const int agg_grid  = 2048;

    // ---- layer 1 ----
    gemm_kernel<128><<<gemm_grid, THREADS, 0, stream>>>(in_feat, W1, norm_out, bufA, n);
    agg_kernel<128, true><<<agg_grid, THREADS, 0, stream>>>(bufA, row_off, csr_src, norm_in, b1, bufB, n);
    // ---- layer 2 ----
    gemm_kernel<128><<<gemm_grid, THREADS, 0, stream>>>(bufB, W2, norm_out, bufA, n);
    agg_kernel<128, true><<<agg_grid, THREADS, 0, stream>>>(bufA, row_off, csr_src, norm_in, b2, bufB, n);
    // ---- layer 3 ----
    gemm_kernel<64><<<gemm_grid, THREADS, 0, stream>>>(bufB, W3, norm_out, bufA, n);
    agg_kernel<64, false><<<agg_grid, THREADS, 0, stream>>>(bufA, row_off, csr_src, norm_in, b3, out, n);
}

// Round 3
// 549.434 us; speedup vs baseline: 3.9466x; 1.6658x over previous
//
#include <hip/hip_runtime.h>

#define THREADS 256
#define SCAN_BLK 1024

typedef __attribute__((ext_vector_type(8))) short short8;
typedef __attribute__((ext_vector_type(4))) float floatx4;

__device__ __forceinline__ ushort f2bf(float f) {
    union { float f; uint u; } v; v.f = f;
    uint u = v.u;
    return (ushort)((u + 0x7FFFu + ((u >> 16) & 1u)) >> 16);   // RNE
}
__device__ __forceinline__ float bf_lo(uint u) {   // low ushort -> float
    union { uint u; float f; } v; v.u = u << 16; return v.f;
}
__device__ __forceinline__ float bf_hi(uint u) {   // high ushort -> float
    union { uint u; float f; } v; v.u = u & 0xFFFF0000u; return v.f;
}

// ================= CSR build =================
__global__ void degree_kernel(const int* __restrict__ src, const int* __restrict__ dst,
                              int* __restrict__ cnt_out, int* __restrict__ cnt_in, int E) {
    int e = blockIdx.x * blockDim.x + threadIdx.x;
    if (e < E) {
        atomicAdd(&cnt_out[src[e]], 1);
        atomicAdd(&cnt_in[dst[e]], 1);
    }
}

__global__ void rnorm_kernel(const int* __restrict__ cnt_out, const int* __restrict__ cnt_in,
                             float* __restrict__ norm_out, float* __restrict__ norm_in, int n) {
    int i = blockIdx.x * blockDim.x + threadIdx.x;
    if (i < n) {
        norm_out[i] = rsqrtf((float)max(cnt_out[i], 1));
        norm_in[i]  = rsqrtf((float)max(cnt_in[i], 1));
    }
}

__global__ void scan_phase1(const int* __restrict__ cnt, int* __restrict__ blk_sums, int n) {
    int base = blockIdx.x * SCAN_BLK;
    int t = threadIdx.x;
    int sum = 0;
    for (int i = t; i < SCAN_BLK; i += THREADS) {
        int idx = base + i;
        sum += (idx < n) ? cnt[idx] : 0;
    }
    __shared__ int wsum[4];
    for (int off = 32; off > 0; off >>= 1) sum += __shfl_down(sum, off);
    if ((t & 63) == 0) wsum[t >> 6] = sum;
    __syncthreads();
    if (t == 0) blk_sums[blockIdx.x] = wsum[0] + wsum[1] + wsum[2] + wsum[3];
}

__global__ void scan_phase2(int* __restrict__ blk_sums, int nb) {
    __shared__ int s[1024];
    int t = threadIdx.x;
    s[t] = (t < nb) ? blk_sums[t] : 0;
    __syncthreads();
    for (int off = 1; off < 1024; off <<= 1) {
        int v = s[t];
        if (t >= off) v += s[t - off];
        __syncthreads();
        s[t] = v;
        __syncthreads();
    }
    if (t < nb) blk_sums[t] = (t == 0) ? 0 : s[t - 1];
}

__global__ void scan_phase3(const int* __restrict__ cnt, const int* __restrict__ blk_sums,
                            int* __restrict__ row_off, int n, int E) {
    __shared__ int ts[THREADS];
    int b = blockIdx.x, t = threadIdx.x;
    int base = b * SCAN_BLK + t * 4;
    int local[4]; int s = 0;
    #pragma unroll
    for (int k = 0; k < 4; ++k) {
        local[k] = s;
        int idx = base + k;
        s += (idx < n) ? cnt[idx] : 0;
    }
    ts[t] = s;
    __syncthreads();
    for (int off = 1; off < THREADS; off <<= 1) {
        int v = ts[t];
        if (t >= off) v += ts[t - off];
        __syncthreads();
        ts[t] = v;
        __syncthreads();
    }
    int excl = (t == 0) ? 0 : ts[t - 1];
    int boff = blk_sums[b];
    #pragma unroll
    for (int k = 0; k < 4; ++k) {
        int idx = base + k;
        if (idx < n) row_off[idx] = boff + excl + local[k];
    }
    if (b == 0 && t == 0) row_off[n] = E;
}

__global__ void fill_kernel(const int* __restrict__ src, const int* __restrict__ dst,
                            const int* __restrict__ row_off, int* __restrict__ cursor,
                            int* __restrict__ csr_src, int E) {
    int e = blockIdx.x * blockDim.x + threadIdx.x;
    if (e < E) {
        int d = dst[e];
        int pos = row_off[d] + atomicAdd(&cursor[d], 1);
        csr_src[pos] = src[e];
    }
}

// ================= W fragment pre-pack =================
// Wpk[(ct*4+kk)*64 + lane][j] = bf16(W[kk*32 + (lane>>4)*8 + j][ct*16 + (lane&15)])
template<int OUT>
__global__ void wpack_kernel(const float* __restrict__ W, ushort* __restrict__ Wpk) {
    int t = blockIdx.x * blockDim.x + threadIdx.x;
    if (t >= (OUT / 16) * 4 * 64) return;
    int lane = t & 63, kk = (t >> 6) & 3, ct = t >> 8;
    int col = ct * 16 + (lane & 15);
    int k0 = kk * 32 + (lane >> 4) * 8;
    #pragma unroll
    for (int j = 0; j < 8; ++j)
        Wpk[t * 8 + j] = f2bf(W[(size_t)(k0 + j) * OUT + col]);
}

// ================= MFMA GEMM: h[node,:] = bf16((x[node,:]*norm[node]) @ W) =================
// 64 nodes per block, 4 waves x 16 rows. x staged (scaled, bf16) in LDS stride 136.
template<int OUT, bool IN_F32>
__global__ __launch_bounds__(256) void mfma_gemm(const void* __restrict__ xv,
                                                 const ushort* __restrict__ Wpk,
                                                 const float* __restrict__ norm,
                                                 ushort* __restrict__ h, int n) {
    __shared__ ushort xs[64 * 136];
    const int t = threadIdx.x;
    const int row0 = blockIdx.x * 64;

    if (IN_F32) {
        const float* x = (const float*)xv;
        #pragma unroll
        for (int i = 0; i < 8; ++i) {
            int e = (i * 256 + t) * 4;
            int row = e >> 7, col = e & 127;
            int gr = min(row0 + row, n - 1);
            float nf = norm[gr];
            float4 v = *(const float4*)(x + (size_t)gr * 128 + col);
            ushort4 p;
            p.x = f2bf(v.x * nf); p.y = f2bf(v.y * nf);
            p.z = f2bf(v.z * nf); p.w = f2bf(v.w * nf);
            *(ushort4*)(&xs[row * 136 + col]) = p;
        }
    } else {
        const ushort* x = (const ushort*)xv;
        #pragma unroll
        for (int i = 0; i < 4; ++i) {
            int e = (i * 256 + t) * 8;
            int row = e >> 7, col = e & 127;
            int gr = min(row0 + row, n - 1);
            float nf = norm[gr];
            uint4 v = *(const uint4*)(x + (size_t)gr * 128 + col);
            uint4 o;
            o.x = f2bf(bf_lo(v.x) * nf) | ((uint)f2bf(bf_hi(v.x) * nf) << 16);
            o.y = f2bf(bf_lo(v.y) * nf) | ((uint)f2bf(bf_hi(v.y) * nf) << 16);
            o.z = f2bf(bf_lo(v.z) * nf) | ((uint)f2bf(bf_hi(v.z) * nf) << 16);
            o.w = f2bf(bf_lo(v.w) * nf) | ((uint)f2bf(bf_hi(v.w) * nf) << 16);
            *(uint4*)(&xs[row * 136 + col]) = o;
        }
    }
    __syncthreads();

    const int wave = t >> 6, lane = t & 63;
    const int r = lane & 15, g = lane >> 4;
    const int nrow0 = row0 + wave * 16;

    short8 a[4];
    #pragma unroll
    for (int kk = 0; kk < 4; ++kk)
        a[kk] = *(const short8*)(&xs[(wave * 16 + r) * 136 + kk * 32 + g * 8]);

    const short8* wp = (const short8*)Wpk;
    #pragma unroll
    for (int ct = 0; ct < OUT / 16; ++ct) {
        floatx4 acc = {0.f, 0.f, 0.f, 0.f};
        #pragma unroll
        for (int kk = 0; kk < 4; ++kk) {
            short8 b = wp[(ct * 4 + kk) * 64 + lane];
            acc = __builtin_amdgcn_mfma_f32_16x16x32_bf16(a[kk], b, acc, 0, 0, 0);
        }
        int col = ct * 16 + r;
        #pragma unroll
        for (int rr = 0; rr < 4; ++rr) {
            int grow = nrow0 + g * 4 + rr;
            if (grow < n) h[(size_t)grow * OUT + col] = f2bf(acc[rr]);
        }
    }
}

// ================= CSR aggregation, 128-wide bf16 in, bf16 out =================
template<bool RELU>
__global__ __launch_bounds__(256) void agg128(const ushort* __restrict__ h,
                                              const int* __restrict__ row_off,
                                              const int* __restrict__ csr_src,
                                              const float* __restrict__ nin,
                                              const float* __restrict__ bias,
                                              ushort* __restrict__ out, int n) {
    const int wave = threadIdx.x >> 6;
    const int lane = threadIdx.x & 63;
    const uint* hu = (const uint*)h;
    for (int node = blockIdx.x * 4 + wave; node < n; node += gridDim.x * 4) {
        int beg = row_off[node], end = row_off[node + 1];
        float a0 = 0.f, a1 = 0.f;
        int j = beg;
        for (; j + 3 < end; j += 4) {
            int s0 = csr_src[j], s1 = csr_src[j + 1], s2 = csr_src[j + 2], s3 = csr_src[j + 3];
            uint u0 = hu[(size_t)s0 * 64 + lane];
            uint u1 = hu[(size_t)s1 * 64 + lane];
            uint u2 = hu[(size_t)s2 * 64 + lane];
            uint u3 = hu[(size_t)s3 * 64 + lane];
            a0 += bf_lo(u0); a1 += bf_hi(u0);
            a0 += bf_lo(u1); a1 += bf_hi(u1);
            a0 += bf_lo(u2); a1 += bf_hi(u2);
            a0 += bf_lo(u3); a1 += bf_hi(u3);
        }
        for (; j < end; ++j) {
            uint u = hu[(size_t)csr_src[j] * 64 + lane];
            a0 += bf_lo(u); a1 += bf_hi(u);
        }
        float nf = nin[node];
        float2 bb = *(const float2*)(bias + 2 * lane);
        float r0 = a0 * nf + bb.x;
        float r1 = a1 * nf + bb.y;
        if (RELU) { r0 = fmaxf(r0, 0.f); r1 = fmaxf(r1, 0.f); }
        ((uint*)out)[(size_t)node * 64 + lane] = (uint)f2bf(r0) | ((uint)f2bf(r1) << 16);
    }
}

// ================= CSR aggregation, 64-wide bf16 in, fp32 out (final) =================
__global__ __launch_bounds__(256) void agg64_final(const ushort* __restrict__ h,
                                                   const int* __restrict__ row_off,
                                                   const int* __restrict__ csr_src,
                                                   const float* __restrict__ nin,
                                                   const float* __restrict__ bias,
                                                   float* __restrict__ out, int n) {
    const int wave = threadIdx.x >> 6;
    const int lane = threadIdx.x & 63;
    const int half = lane >> 5, u5 = lane & 31;
    const uint* hu = (const uint*)h;
    for (int node = blockIdx.x * 4 + wave; node < n; node += gridDim.x * 4) {
        int beg = row_off[node], end = row_off[node + 1];
        float a0 = 0.f, a1 = 0.f;
        int j = beg + half;
        for (; j + 2 < end; j += 4) {  // this half handles j, j+2
            int sA = csr_src[j], sB = csr_src[j + 2];
            uint uA = hu[(size_t)sA * 32 + u5];
            uint uB = hu[(size_t)sB * 32 + u5];
            a0 += bf_lo(uA); a1 += bf_hi(uA);
            a0 += bf_lo(uB); a1 += bf_hi(uB);
        }
        if (j < end) {
            uint u = hu[(size_t)csr_src[j] * 32 + u5];
            a0 += bf_lo(u); a1 += bf_hi(u);
        }
        float o0 = a0 + __shfl(a0, u5 + 32);
        float o1 = a1 + __shfl(a1, u5 + 32);
        if (lane < 32) {
            float nf = nin[node];
            float2 bb = *(const float2*)(bias + 2 * u5);
            float2 r;
            r.x = o0 * nf + bb.x;
            r.y = o1 * nf + bb.y;
            *(float2*)(out + (size_t)node * 64 + 2 * u5) = r;
        }
    }
}

extern "C" void kernel_launch(void* const* d_in, const int* in_sizes, int n_in,
                              void* d_out, int out_size, void* d_ws, size_t ws_size,
                              hipStream_t stream) {
    const float* in_feat = (const float*)d_in[0];
    const int*   src     = (const int*)d_in[1];
    const int*   dst     = (const int*)d_in[2];
    const float* W1      = (const float*)d_in[3];
    const float* b1      = (const float*)d_in[4];
    const float* W2      = (const float*)d_in[5];
    const float* b2      = (const float*)d_in[6];
    const float* W3      = (const float*)d_in[7];
    const float* b3      = (const float*)d_in[8];

    const int n = in_sizes[0] / 128;
    const int E = in_sizes[1];
    float* out = (float*)d_out;

    // ws layout: norm_out[n], norm_in[n] (f32); row_off[n+2], csr_src[E] (int);
    //            Wpk1[16384], Wpk2[16384], Wpk3[8192] (ushort); bufA[n*128], bufB[n*128] (ushort)
    float* ws       = (float*)d_ws;
    float* norm_out = ws;
    float* norm_in  = ws + n;
    int*   row_off  = (int*)(ws + 2 * (size_t)n);
    int*   csr_src  = row_off + (n + 2);
    ushort* Wpk1    = (ushort*)(csr_src + E);
    ushort* Wpk2    = Wpk1 + 128 * 128;
    ushort* Wpk3    = Wpk2 + 128 * 128;
    ushort* bufA    = Wpk3 + 128 * 64;
    ushort* bufB    = bufA + (size_t)n * 128;
    // CSR-build temporaries overlaid on bufA (dead before gemm layer 1 writes bufA)
    int* cnt_out  = (int*)bufA;
    int* cnt_in   = cnt_out + n;
    int* cursor   = cnt_in + n;
    int* blk_sums = cursor + n;

    const int nb = (n + SCAN_BLK - 1) / SCAN_BLK;

    // ---- CSR build + norms + W pack (reused by all layers) ----
    hipMemsetAsync(cnt_out, 0, 3 * (size_t)n * sizeof(int), stream);
    degree_kernel<<<(E + THREADS - 1) / THREADS, THREADS, 0, stream>>>(src, dst, cnt_out, cnt_in, E);
    rnorm_kernel<<<(n + THREADS - 1) / THREADS, THREADS, 0, stream>>>(cnt_out, cnt_in, norm_out, norm_in, n);
    scan_phase1<<<nb, THREADS, 0, stream>>>(cnt_in, blk_sums, n);
    scan_phase2<<<1, 1024, 0, stream>>>(blk_sums, nb);
    scan_phase3<<<nb, THREADS, 0, stream>>>(cnt_in, blk_sums, row_off, n, E);
    fill_kernel<<<(E + THREADS - 1) / THREADS, THREADS, 0, stream>>>(src, dst, row_off, cursor, csr_src, E);
    wpack_kernel<128><<<8, THREADS, 0, stream>>>(W1, Wpk1);
    wpack_kernel<128><<<8, THREADS, 0, stream>>>(W2, Wpk2);
    wpack_kernel<64><<<4, THREADS, 0, stream>>>(W3, Wpk3);

    const int gemm_grid = (n + 63) / 64;
    const int agg_grid  = 4096;

    // ---- layer 1 ----
    mfma_gemm<128, true><<<gemm_grid, THREADS, 0, stream>>>(in_feat, Wpk1, norm_out, bufA, n);
    agg128<true><<<agg_grid, THREADS, 0, stream>>>(bufA, row_off, csr_src, norm_in, b1, bufB, n);
    // ---- layer 2 ----
    mfma_gemm<128, false><<<gemm_grid, THREADS, 0, stream>>>(bufB, Wpk2, norm_out, bufA, n);
    agg128<true><<<agg_grid, THREADS, 0, stream>>>(bufA, row_off, csr_src, norm_in, b2, bufB, n);
    // ---- layer 3 ----
    mfma_gemm<64, false><<<gemm_grid, THREADS, 0, stream>>>(bufB, Wpk3, norm_out, bufA, n);
    agg64_final<<<agg_grid, THREADS, 0, stream>>>(bufA, row_off, csr_src, norm_in, b3, out, n);
}